// Round 20
// baseline (25.473 us; speedup 1.0000x reference)
//
#include <hip/hip_runtime.h>
#include <math.h>

// NUFFT forward via separable phase + bf16 MFMA.
// ksp[c,k] = sum_x Ex[k,x] * ( sum_y img[c,x,y] * Ey[k,y] )
// R20 = R19 with staging replaced by global_load_lds DMA from a PRE-SWIZZLED
// bf16 image in d_ws (built by a tiny cvt kernel each launch; 512 KB,
// in-bounds: ws >= 268 MB per poison-fill evidence). Rule #21: linear LDS
// dest + swizzle pre-applied at the global source + swizzled ds_read.
// Staging: 8 x 1KB DMA per wave, zero VGPR round-trip, zero VALU; the
// in-register Ey recurrence overlaps the DMA. Compute/epilogue = R19.

#define K_TOTAL 8192
#define KB      128         // k's per block (8 octs of 16)
#define NX      128
#define NY      128

typedef short  bf16x8 __attribute__((ext_vector_type(8)));
typedef float  f32x4  __attribute__((ext_vector_type(4)));
typedef unsigned int u32;

__device__ inline unsigned short f32_to_bf16_rne(float f) {
    unsigned int u = __float_as_uint(f);
    u += 0x7FFFu + ((u >> 16) & 1u);
    return (unsigned short)(u >> 16);
}
__device__ inline unsigned pack2(float a, float b) {
    return (unsigned)f32_to_bf16_rne(a) | ((unsigned)f32_to_bf16_rne(b) << 16);
}
__device__ inline void gload_lds16(const void* g, void* l) {
    __builtin_amdgcn_global_load_lds(
        (const __attribute__((address_space(1))) u32*)g,
        (__attribute__((address_space(3))) u32*)l, 16, 0, 0);
}

// ---- pre-kernel: img fp32 -> bf16, pre-swizzled, into d_ws ----
// d_ws byte layout: c*65536 + plane*32768 + row*256 + ((col4*8)^((row&15)<<4))
__global__ void cvt_swz_kernel(const float* __restrict__ imgR,
                               const float* __restrict__ imgI,
                               unsigned short* __restrict__ ws) {
    const int tid   = blockIdx.x * 256 + threadIdx.x;   // 0..65535
    const int col4  = tid & 31;
    const int row   = (tid >> 5) & 127;
    const int plane = (tid >> 12) & 1;
    const int c     = tid >> 13;
    const float* src = plane ? imgI : imgR;
    const float4 v = *(const float4*)(src + (c * NX + row) * NY + col4 * 4);
    uint2 p;
    p.x = pack2(v.x, v.y);
    p.y = pack2(v.z, v.w);
    char* dst = (char*)ws + c * 65536 + plane * 32768 + row * 256
              + ((col4 * 8) ^ ((row & 15) << 4));
    *(uint2*)dst = p;
}

__global__ __launch_bounds__(512, 2) void nufft_mfma_kernel(
    const unsigned short* __restrict__ ws,
    const float* __restrict__ trj,
    float* __restrict__ out)
{
    // one-coil slab: [plane RI][128 rows * 256 B], swizzled image. 64 KB.
    __shared__ __align__(1024) unsigned short slab[2][128 * 128];

    const int tid = threadIdx.x;
    const int bid = blockIdx.x;
    const int c   = bid >> 6;          // coil 0..7
    const int kg0 = (bid & 63) * KB;   // base k of this block

    const int wave = tid >> 6;      // 0..7 == k-oct
    const int lane = tid & 63;
    const int l15  = lane & 15;
    const int lg   = lane >> 4;     // 0..3

    // ---- staging: pure DMA. wave stages LDS bytes [wave*8K, wave*8K+8K)
    // from the identical linear range of this coil's pre-swizzled ws image.
    {
        const char* gbase = (const char*)ws + (size_t)c * 65536
                          + (size_t)wave * 8192 + (size_t)lane * 16;
        char* lbase = (char*)&slab[0][0] + wave * 8192;   // wave-uniform dest
#pragma unroll
        for (int j = 0; j < 8; ++j)
            gload_lds16(gbase + j * 1024, lbase + j * 1024);
    }

    // ---- Ey A-fragments in registers via phase recurrence (overlaps DMA) ----
    // A layout (16x16x32): row = lane&15 -> k = kg0 + wave*16 + l15;
    // k slot y = ys*32 + lg*8 + m. Walk m by cmul with exp(-2πi ky/128).
    bf16x8 aR[4], aI[4];
    {
        const float ky = trj[(kg0 + wave * 16 + l15) * 2 + 1];
        float u = -ky * (1.0f / 128.0f); u -= floorf(u);
        float s1i, s1r; __sincosf(6.283185307179586f * u, &s1i, &s1r);
#pragma unroll
        for (int ys = 0; ys < 4; ++ys) {
            const int y0 = ys * 32 + lg * 8;
            float t = -ky * (float)(y0 - 64) * (1.0f / 128.0f); t -= floorf(t);
            float ci_, cr_; __sincosf(6.283185307179586f * t, &ci_, &cr_);
#pragma unroll
            for (int m = 0; m < 8; ++m) {
                aR[ys][m] = (short)f32_to_bf16_rne(cr_);
                aI[ys][m] = (short)f32_to_bf16_rne(ci_);
                const float nr = cr_ * s1r - ci_ * s1i;
                ci_ = cr_ * s1i + ci_ * s1r;
                cr_ = nr;
            }
        }
    }

    // kx preload for stage C: k = kg0 + wave*16 + lg*4 + j
    float kxv[4];
#pragma unroll
    for (int j = 0; j < 4; ++j)
        kxv[j] = trj[(kg0 + wave * 16 + lg * 4 + j) * 2 + 0];

    __syncthreads();   // drains DMA (vmcnt) + makes slab visible to all waves

    // ---- barrier-free compute: 8 x-tiles of pure ds_read + MFMA + cmul ----
    const char* sbR = (const char*)&slab[0][0];
    const char* sbI = (const char*)&slab[1][0];

    f32x4 outRe = {0,0,0,0};
    f32x4 outIm = {0,0,0,0};

#pragma unroll
    for (int nt = 0; nt < 8; ++nt) {
        const int x    = nt * 16 + l15;
        const int rowb = x * 256;

        f32x4 P = {0,0,0,0}, Q = {0,0,0,0}, U = {0,0,0,0}, V = {0,0,0,0};
#pragma unroll
        for (int ys = 0; ys < 4; ++ys) {
            const int inb = (lg * 16 + ys * 64) ^ (l15 << 4);
            const bf16x8 bR = *(const bf16x8*)(sbR + rowb + inb);
            const bf16x8 bI = *(const bf16x8*)(sbI + rowb + inb);
            P = __builtin_amdgcn_mfma_f32_16x16x32_bf16(aR[ys], bR, P, 0, 0, 0);
            Q = __builtin_amdgcn_mfma_f32_16x16x32_bf16(aI[ys], bI, Q, 0, 0, 0);
            U = __builtin_amdgcn_mfma_f32_16x16x32_bf16(aR[ys], bI, U, 0, 0, 0);
            V = __builtin_amdgcn_mfma_f32_16x16x32_bf16(aI[ys], bR, V, 0, 0, 0);
        }

        const float rx = (float)(x - 64) * (1.0f / 128.0f);
#pragma unroll
        for (int j = 0; j < 4; ++j) {
            float t = -kxv[j] * rx; t -= floorf(t);
            float eI_, eR_; __sincosf(6.283185307179586f * t, &eI_, &eR_);
            const float TR = P[j] - Q[j];
            const float TI = U[j] + V[j];
            outRe[j] += eR_ * TR - eI_ * TI;
            outIm[j] += eR_ * TI + eI_ * TR;
        }
    }

    // ---- reduce over the 16 x-lanes; lanes with l15==0 write ----
#pragma unroll
    for (int j = 0; j < 4; ++j) {
        float r_ = outRe[j];
        float i_ = outIm[j];
#pragma unroll
        for (int m = 1; m < 16; m <<= 1) {
            r_ += __shfl_xor(r_, m, 64);
            i_ += __shfl_xor(i_, m, 64);
        }
        if (l15 == 0) {
            const int kg = kg0 + wave * 16 + lg * 4 + j;
            ((float2*)out)[c * K_TOTAL + kg] = make_float2(r_, i_);
        }
    }
}

extern "C" void kernel_launch(void* const* d_in, const int* in_sizes, int n_in,
                              void* d_out, int out_size, void* d_ws, size_t ws_size,
                              hipStream_t stream) {
    const float* imgR = (const float*)d_in[0];
    const float* imgI = (const float*)d_in[1];
    const float* trj  = (const float*)d_in[2];
    float* out = (float*)d_out;
    unsigned short* ws = (unsigned short*)d_ws;   // 512 KiB used, in-bounds

    hipLaunchKernelGGL(cvt_swz_kernel, dim3(256), dim3(256), 0, stream,
                       imgR, imgI, ws);
    hipLaunchKernelGGL(nufft_mfma_kernel, dim3(512), dim3(512), 0, stream,
                       ws, trj, out);
}